// Round 1
// baseline (1545.043 us; speedup 1.0000x reference)
//
#include <hip/hip_runtime.h>
#include <hip/hip_bf16.h>

// ---------------- problem constants ----------------
#define BB   2
#define TT   8
#define YY   128
#define XX   128
#define CINv 128
#define COUTv 64
#define YOv  255
#define XOv  255
#define NVOX 262144
#define OUT_SITES (BB*TT*YOv*XOv)            // 1,040,400
#define OUT_ELEMS ((size_t)OUT_SITES*COUTv)  // 66,585,600

typedef float  f32x4  __attribute__((ext_vector_type(4)));
typedef __bf16 bf16x8 __attribute__((ext_vector_type(8)));
typedef unsigned int u32x4 __attribute__((ext_vector_type(4)));

union FragU { u32x4 u; bf16x8 b; };
union Pack8 { unsigned short s[8]; u32x4 u; };

// ---------------- workspace layout (bytes) ----------------
// zeroed prefix: D (fp32 dense input grid) + occ + stats
constexpr size_t OFF_D     = 0;                                  // 262144*128*4 = 134,217,728
constexpr size_t OFF_OCC   = 134217728;                          // 262144*4 = 1,048,576
constexpr size_t OFF_STATS = OFF_OCC + 1048576;                  // sum[64]@0, sq[64]@256, n@512
constexpr size_t ZERO_BYTES= OFF_STATS + 1024;
constexpr size_t OFF_MASK  = ZERO_BYTES;                         // 1,040,400 (pad 1 MiB)
constexpr size_t OFF_DBF   = OFF_MASK + 1048576;                 // 262144*128*2 = 67,108,864
constexpr size_t OFF_PB    = OFF_DBF + 67108864;                 // 27*16*64*8*2 = 442,368
constexpr size_t OFF_SS    = OFF_PB + 442368;                    // scale[64], shift[64]

__device__ __forceinline__ unsigned short f2bf(float f) {
    unsigned u = __float_as_uint(f);
    u += 0x7fffu + ((u >> 16) & 1u);       // round-to-nearest-even
    return (unsigned short)(u >> 16);
}

// ---------------- pass 1: scatter feats into dense grid ----------------
__global__ __launch_bounds__(256) void k_scatter(
    const float* __restrict__ feats,
    const int* __restrict__ cb, const int* __restrict__ ct,
    const int* __restrict__ cy, const int* __restrict__ cx,
    float* __restrict__ D, unsigned int* __restrict__ occ)
{
    int tid = blockIdx.x * 256 + threadIdx.x;   // n*32 + c4 (8,388,608 threads)
    int n  = tid >> 5;
    int c4 = (tid & 31) * 4;
    int site = ((cb[n] * TT + ct[n]) * YY + cy[n]) * XX + cx[n];
    const float4 v = *(const float4*)(feats + (size_t)n * CINv + c4);
    float* dst = D + (size_t)site * CINv + c4;
    unsafeAtomicAdd(dst + 0, v.x);
    unsafeAtomicAdd(dst + 1, v.y);
    unsafeAtomicAdd(dst + 2, v.z);
    unsafeAtomicAdd(dst + 3, v.w);
    if (c4 == 0) atomicAdd(occ + site, 1u);
}

// ---------------- pass 2: fp32 grid -> bf16 grid ----------------
__global__ __launch_bounds__(256) void k_convert(
    const float* __restrict__ D, unsigned short* __restrict__ Dbf)
{
    size_t i = ((size_t)blockIdx.x * 256 + threadIdx.x) * 8;   // 4,194,304 threads
    float4 a = *(const float4*)(D + i);
    float4 b = *(const float4*)(D + i + 4);
    Pack8 p;
    p.s[0] = f2bf(a.x); p.s[1] = f2bf(a.y); p.s[2] = f2bf(a.z); p.s[3] = f2bf(a.w);
    p.s[4] = f2bf(b.x); p.s[5] = f2bf(b.y); p.s[6] = f2bf(b.z); p.s[7] = f2bf(b.w);
    *(u32x4*)(Dbf + i) = p.u;
}

// ---------------- pass 3: pack weights into MFMA B-fragments ----------------
// PB layout: [w(27)][kc(4)][nt(4)][lane(64)][8 bf16]
// B-frag (16x16x32): lane holds B[k=(lane>>4)*8+j][n=lane&15]
__global__ __launch_bounds__(64) void k_pack(
    const float* __restrict__ W, unsigned short* __restrict__ PB)
{
    int f = blockIdx.x;                 // 0..431 = w*16 + kc*4 + nt
    int w  = f >> 4;
    int kc = (f >> 2) & 3;
    int nt = f & 3;
    int lane = threadIdx.x;
    int q = lane >> 4, col = lane & 15;
    Pack8 p;
    #pragma unroll
    for (int j = 0; j < 8; ++j) {
        int k  = kc * 32 + q * 8 + j;
        int nn = nt * 16 + col;
        p.s[j] = f2bf(W[((size_t)w * CINv + k) * COUTv + nn]);
    }
    *(u32x4*)(PB + ((size_t)f * 64 + lane) * 8) = p.u;
}

// ---------------- pass 4: active-site mask + count ----------------
__global__ __launch_bounds__(256) void k_mask(
    const unsigned int* __restrict__ occ,
    unsigned char* __restrict__ mask, unsigned int* __restrict__ ncnt)
{
    int s = blockIdx.x * 256 + threadIdx.x;
    bool found = false;
    if (s < OUT_SITES) {
        int xo = s % XOv; int r = s / XOv;
        int yo = r % YOv; r /= YOv;
        int to = r & 7;   int b = r >> 3;
        int cts[3]; int ntc = 0;
        for (int kt = 0; kt < 3; ++kt) { int c = to + 1 - kt; if (c >= 0 && c < TT) cts[ntc++] = c; }
        int cys[2]; int nyc;
        if (yo & 1) { cys[0] = (yo + 1) >> 1; cys[1] = (yo - 1) >> 1; nyc = 2; }
        else        { cys[0] = yo >> 1; nyc = 1; }
        int cxs[2]; int nxc;
        if (xo & 1) { cxs[0] = (xo + 1) >> 1; cxs[1] = (xo - 1) >> 1; nxc = 2; }
        else        { cxs[0] = xo >> 1; nxc = 1; }
        for (int i = 0; i < ntc && !found; ++i)
            for (int j = 0; j < nyc && !found; ++j)
                for (int k = 0; k < nxc && !found; ++k)
                    if (occ[((b * TT + cts[i]) * YY + cys[j]) * XX + cxs[k]]) found = true;
        mask[s] = found ? 1 : 0;
    }
    unsigned long long bal = __ballot(found);
    if ((threadIdx.x & 63) == 0) {
        unsigned c = (unsigned)__popcll(bal);
        if (c) atomicAdd(ncnt, c);
    }
}

// ---------------- pass 5: MFMA gather transpose-conv ----------------
// Wave: 16 output sites (one x-parity run) x 64 couts, K=128, <=12 taps.
// A-frag (16x16x32): lane holds A[m=lane&15][k=(lane>>4)*8+j]
// C/D: col=lane&15, row=(lane>>4)*4+reg
__global__ __launch_bounds__(256) void k_conv(
    const unsigned short* __restrict__ Dbf,
    const unsigned short* __restrict__ PB,
    float* __restrict__ out)
{
    const int lane = threadIdx.x & 63;
    const int wave = threadIdx.x >> 6;
    const int chunk  = ((blockIdx.x & 3) << 2) | wave;   // 0..15
    const int row_id = blockIdx.x >> 2;                  // 0..4079
    const int yo = row_id % YOv;
    int r2 = row_id / YOv;
    const int to = r2 & 7;
    const int b  = r2 >> 3;
    const int px  = chunk & 1;
    const int cb8 = chunk >> 1;
    const int m = lane & 15, q = lane >> 4;
    const int cxm = cb8 * 16 + m;

    int xcx[2], xkx[2], nx;
    if (px == 0) { nx = 1; xcx[0] = cxm; xkx[0] = 1; }
    else { nx = 2; xcx[0] = (cxm + 1 > 127) ? 127 : cxm + 1; xkx[0] = 0; xcx[1] = cxm; xkx[1] = 2; }
    int ycy[2], yky[2], ny;
    if ((yo & 1) == 0) { ny = 1; ycy[0] = yo >> 1; yky[0] = 1; }
    else { ny = 2; ycy[0] = (yo + 1) >> 1; yky[0] = 0; ycy[1] = (yo - 1) >> 1; yky[1] = 2; }

    f32x4 acc[4];
    #pragma unroll
    for (int i = 0; i < 4; ++i) acc[i] = (f32x4){0.f, 0.f, 0.f, 0.f};

    for (int kt = 0; kt < 3; ++kt) {
        int ct = to + 1 - kt;
        if (ct < 0 || ct >= TT) continue;
        for (int iy = 0; iy < ny; ++iy) {
            int wbase = (kt * 3 + yky[iy]) * 3;
            size_t plane = ((size_t)((b * TT + ct) * YY + ycy[iy])) * XX;
            for (int ix = 0; ix < nx; ++ix) {
                const unsigned short* arow = Dbf + (plane + (size_t)xcx[ix]) * CINv;
                FragU A[4];
                #pragma unroll
                for (int kc = 0; kc < 4; ++kc)
                    A[kc].u = *(const u32x4*)(arow + kc * 32 + q * 8);
                const unsigned short* pb = PB + ((size_t)(wbase + xkx[ix]) * 16 * 64) * 8;
                #pragma unroll
                for (int nt = 0; nt < 4; ++nt) {
                    #pragma unroll
                    for (int kc = 0; kc < 4; ++kc) {
                        FragU Bf;
                        Bf.u = *(const u32x4*)(pb + ((size_t)(kc * 4 + nt) * 64 + lane) * 8);
                        acc[nt] = __builtin_amdgcn_mfma_f32_16x16x32_bf16(A[kc].b, Bf.b, acc[nt], 0, 0, 0);
                    }
                }
            }
        }
    }

    size_t rowbase = ((size_t)((b * TT + to) * YOv + yo)) * XOv;
    #pragma unroll
    for (int nt = 0; nt < 4; ++nt) {
        int c = nt * 16 + m;
        #pragma unroll
        for (int i = 0; i < 4; ++i) {
            int rr = q * 4 + i;
            int xo = 2 * (cb8 * 16 + rr) + px;
            if (xo < XOv) out[(rowbase + xo) * COUTv + c] = acc[nt][i];
        }
    }
}

// ---------------- pass 6: per-channel sum / sumsq ----------------
__global__ __launch_bounds__(256) void k_stats(
    const float* __restrict__ out, float* __restrict__ gsum, float* __restrict__ gsq)
{
    size_t tid = (size_t)blockIdx.x * 256 + threadIdx.x;
    size_t stride = (size_t)gridDim.x * 256;            // multiple of 64
    int c = threadIdx.x & 63;
    float s = 0.f, s2 = 0.f;
    for (size_t e = tid; e < OUT_ELEMS; e += stride) {
        float v = out[e];
        s += v; s2 += v * v;
    }
    __shared__ float sh[128];
    if (threadIdx.x < 128) sh[threadIdx.x] = 0.f;
    __syncthreads();
    unsafeAtomicAdd(&sh[c], s);
    unsafeAtomicAdd(&sh[64 + c], s2);
    __syncthreads();
    if (threadIdx.x < 64) {
        unsafeAtomicAdd(&gsum[threadIdx.x], sh[threadIdx.x]);
        unsafeAtomicAdd(&gsq[threadIdx.x], sh[64 + threadIdx.x]);
    }
}

// ---------------- pass 7: finalize BN stats ----------------
__global__ __launch_bounds__(64) void k_final(
    const float* __restrict__ gsum, const float* __restrict__ gsq,
    const unsigned int* __restrict__ ncnt,
    const float* __restrict__ gamma, const float* __restrict__ beta,
    float* __restrict__ scale, float* __restrict__ shift)
{
    int c = threadIdx.x;
    float nf = (float)max(*ncnt, 1u);
    float mean = gsum[c] / nf;
    float var  = gsq[c] / nf - mean * mean;
    float rstd = rsqrtf(var + 1e-5f);
    float sc = rstd * gamma[c];
    scale[c] = sc;
    shift[c] = beta[c] - mean * sc;
}

// ---------------- pass 8: normalize + mask + relu (in place) ----------------
__global__ __launch_bounds__(256) void k_norm(
    float* __restrict__ out, const unsigned char* __restrict__ mask,
    const float* __restrict__ scale, const float* __restrict__ shift)
{
    __shared__ float ssc[64], ssh[64];
    if (threadIdx.x < 64) { ssc[threadIdx.x] = scale[threadIdx.x]; ssh[threadIdx.x] = shift[threadIdx.x]; }
    __syncthreads();
    size_t t = (size_t)blockIdx.x * 256 + threadIdx.x;   // 16,646,400 threads exactly
    size_t e = t * 4;
    float4 v = ((float4*)out)[t];
    int c = (int)(e & 63);
    size_t site = e >> 6;
    if (mask[site]) {
        v.x = fmaxf(fmaf(v.x, ssc[c + 0], ssh[c + 0]), 0.f);
        v.y = fmaxf(fmaf(v.y, ssc[c + 1], ssh[c + 1]), 0.f);
        v.z = fmaxf(fmaf(v.z, ssc[c + 2], ssh[c + 2]), 0.f);
        v.w = fmaxf(fmaf(v.w, ssc[c + 3], ssh[c + 3]), 0.f);
    } else {
        v.x = v.y = v.z = v.w = 0.f;
    }
    ((float4*)out)[t] = v;
}

// ---------------- launch ----------------
extern "C" void kernel_launch(void* const* d_in, const int* in_sizes, int n_in,
                              void* d_out, int out_size, void* d_ws, size_t ws_size,
                              hipStream_t stream)
{
    const float* feats = (const float*)d_in[0];
    const float* W     = (const float*)d_in[1];
    const float* gamma = (const float*)d_in[2];
    const float* beta  = (const float*)d_in[3];
    const int* cb = (const int*)d_in[4];
    const int* ct = (const int*)d_in[5];
    const int* cy = (const int*)d_in[6];
    const int* cx = (const int*)d_in[7];
    float* out = (float*)d_out;

    char* ws = (char*)d_ws;
    float*          D    = (float*)(ws + OFF_D);
    unsigned int*   occ  = (unsigned int*)(ws + OFF_OCC);
    float*          gsum = (float*)(ws + OFF_STATS);
    float*          gsq  = gsum + 64;
    unsigned int*   ncnt = (unsigned int*)(ws + OFF_STATS + 512);
    unsigned char*  mask = (unsigned char*)(ws + OFF_MASK);
    unsigned short* Dbf  = (unsigned short*)(ws + OFF_DBF);
    unsigned short* PB   = (unsigned short*)(ws + OFF_PB);
    float*          scale= (float*)(ws + OFF_SS);
    float*          shift= scale + 64;

    hipMemsetAsync(d_ws, 0, ZERO_BYTES, stream);

    k_scatter<<<NVOX * 32 / 256, 256, 0, stream>>>(feats, cb, ct, cy, cx, D, occ);
    k_convert<<<(NVOX * CINv / 8) / 256, 256, 0, stream>>>(D, Dbf);
    k_pack<<<27 * 16, 64, 0, stream>>>(W, PB);
    k_mask<<<(OUT_SITES + 255) / 256, 256, 0, stream>>>(occ, mask, ncnt);
    k_conv<<<BB * TT * YOv * 4, 256, 0, stream>>>(Dbf, PB, out);
    k_stats<<<2048, 256, 0, stream>>>(out, gsum, gsq);
    k_final<<<1, 64, 0, stream>>>(gsum, gsq, ncnt, gamma, beta, scale, shift);
    k_norm<<<(int)(OUT_ELEMS / 4 / 256), 256, 0, stream>>>(out, mask, scale, shift);
}

// Round 2
// 1118.952 us; speedup vs baseline: 1.3808x; 1.3808x over previous
//
#include <hip/hip_runtime.h>
#include <hip/hip_bf16.h>

// ---------------- problem constants ----------------
#define BB   2
#define TT   8
#define YY   128
#define XX   128
#define CINv 128
#define COUTv 64
#define YOv  255
#define XOv  255
#define NVOX 262144
#define NSITES (BB*TT*YY*XX)                 // 262,144 input sites
#define CAP  16
#define OUT_SITES (BB*TT*YOv*XOv)            // 1,040,400
#define OUT_ELEMS ((size_t)OUT_SITES*COUTv)  // 66,585,600

typedef float  f32x4  __attribute__((ext_vector_type(4)));
typedef __bf16 bf16x8 __attribute__((ext_vector_type(8)));
typedef unsigned int u32x4 __attribute__((ext_vector_type(4)));

union FragU { u32x4 u; bf16x8 b; };
union Pack8 { unsigned short s[8]; u32x4 u; };

// ---------------- workspace layout (bytes) ----------------
// zeroed prefix: stats + per-site counts
constexpr size_t OFF_STATS = 0;                         // gsum[64]@0, gsq[64]@256, ncnt@512
constexpr size_t OFF_CNT   = 1024;                      // 262144*4 = 1,048,576
constexpr size_t ZERO_BYTES= OFF_CNT + 1048576;         // 1,049,600
constexpr size_t OFF_IDX   = ZERO_BYTES;                // 262144*16*4 = 16,777,216
constexpr size_t OFF_DBF   = OFF_IDX + 16777216;        // 262144*128*2 = 67,108,864
constexpr size_t OFF_PB    = OFF_DBF + 67108864;        // 27*16*64*8*2 = 442,368
constexpr size_t OFF_MASK  = OFF_PB + 442368;           // 1,040,400 (pad 1 MiB)
constexpr size_t OFF_SS    = OFF_MASK + 1048576;        // scale[64], shift[64]

__device__ __forceinline__ unsigned short f2bf(float f) {
    unsigned u = __float_as_uint(f);
    u += 0x7fffu + ((u >> 16) & 1u);       // round-to-nearest-even
    return (unsigned short)(u >> 16);
}

// ---------------- pass 1: per-site voxel lists ----------------
__global__ __launch_bounds__(256) void k_count(
    const int* __restrict__ cb, const int* __restrict__ ct,
    const int* __restrict__ cy, const int* __restrict__ cx,
    unsigned int* __restrict__ cnt, int* __restrict__ idx)
{
    int n = blockIdx.x * 256 + threadIdx.x;     // NVOX threads
    int site = ((cb[n] * TT + ct[n]) * YY + cy[n]) * XX + cx[n];
    unsigned slot = atomicAdd(cnt + site, 1u);
    if (slot < CAP) idx[site * CAP + slot] = n;  // P(overflow) ~ 4e-9 for Poisson(1)
}

// ---------------- pass 2: gather-sum feats -> bf16 dense grid ----------------
__global__ __launch_bounds__(256) void k_gather(
    const float* __restrict__ feats,
    const unsigned int* __restrict__ cnt, const int* __restrict__ idx,
    unsigned short* __restrict__ Dbf)
{
    int tid = blockIdx.x * 256 + threadIdx.x;   // NSITES*16 = 4,194,304 threads
    int site = tid >> 4;
    int c8 = (tid & 15) * 8;
    unsigned c = cnt[site]; if (c > CAP) c = CAP;
    float a[8] = {0.f,0.f,0.f,0.f,0.f,0.f,0.f,0.f};
    const int* ip = idx + (size_t)site * CAP;
    for (unsigned v = 0; v < c; ++v) {
        int n = ip[v];
        const float4 f0 = *(const float4*)(feats + (size_t)n * CINv + c8);
        const float4 f1 = *(const float4*)(feats + (size_t)n * CINv + c8 + 4);
        a[0] += f0.x; a[1] += f0.y; a[2] += f0.z; a[3] += f0.w;
        a[4] += f1.x; a[5] += f1.y; a[6] += f1.z; a[7] += f1.w;
    }
    Pack8 p;
    #pragma unroll
    for (int j = 0; j < 8; ++j) p.s[j] = f2bf(a[j]);
    *(u32x4*)(Dbf + (size_t)site * CINv + c8) = p.u;
}

// ---------------- pass 3: pack weights into MFMA B-fragments ----------------
// PB layout: [w(27)][kc(4)][nt(4)][lane(64)][8 bf16]
// B-frag (16x16x32): lane holds B[k=(lane>>4)*8+j][n=lane&15]
__global__ __launch_bounds__(64) void k_pack(
    const float* __restrict__ W, unsigned short* __restrict__ PB)
{
    int f = blockIdx.x;                 // 0..431 = w*16 + kc*4 + nt
    int w  = f >> 4;
    int kc = (f >> 2) & 3;
    int nt = f & 3;
    int lane = threadIdx.x;
    int q = lane >> 4, col = lane & 15;
    Pack8 p;
    #pragma unroll
    for (int j = 0; j < 8; ++j) {
        int k  = kc * 32 + q * 8 + j;
        int nn = nt * 16 + col;
        p.s[j] = f2bf(W[((size_t)w * CINv + k) * COUTv + nn]);
    }
    *(u32x4*)(PB + ((size_t)f * 64 + lane) * 8) = p.u;
}

// ---------------- pass 4: active-site mask + count ----------------
__global__ __launch_bounds__(256) void k_mask(
    const unsigned int* __restrict__ occ,
    unsigned char* __restrict__ mask, unsigned int* __restrict__ ncnt)
{
    int s = blockIdx.x * 256 + threadIdx.x;
    bool found = false;
    if (s < OUT_SITES) {
        int xo = s % XOv; int r = s / XOv;
        int yo = r % YOv; r /= YOv;
        int to = r & 7;   int b = r >> 3;
        int cts[3]; int ntc = 0;
        for (int kt = 0; kt < 3; ++kt) { int c = to + 1 - kt; if (c >= 0 && c < TT) cts[ntc++] = c; }
        int cys[2]; int nyc;
        if (yo & 1) { cys[0] = (yo + 1) >> 1; cys[1] = (yo - 1) >> 1; nyc = 2; }
        else        { cys[0] = yo >> 1; nyc = 1; }
        int cxs[2]; int nxc;
        if (xo & 1) { cxs[0] = (xo + 1) >> 1; cxs[1] = (xo - 1) >> 1; nxc = 2; }
        else        { cxs[0] = xo >> 1; nxc = 1; }
        for (int i = 0; i < ntc && !found; ++i)
            for (int j = 0; j < nyc && !found; ++j)
                for (int k = 0; k < nxc && !found; ++k)
                    if (occ[((b * TT + cts[i]) * YY + cys[j]) * XX + cxs[k]]) found = true;
        mask[s] = found ? 1 : 0;
    }
    unsigned long long bal = __ballot(found);
    if ((threadIdx.x & 63) == 0) {
        unsigned c = (unsigned)__popcll(bal);
        if (c) atomicAdd(ncnt, c);
    }
}

// ---------------- pass 5: MFMA gather transpose-conv + fused stats ----------------
// Wave: 16 output sites (one x-parity run) x 64 couts, K=128, <=12 taps.
// A-frag (16x16x32): lane holds A[m=lane&15][k=(lane>>4)*8+j]
// C/D: col=lane&15, row=(lane>>4)*4+reg
__global__ __launch_bounds__(256) void k_conv(
    const unsigned short* __restrict__ Dbf,
    const unsigned short* __restrict__ PB,
    float* __restrict__ out,
    float* __restrict__ gsum, float* __restrict__ gsq)
{
    const int lane = threadIdx.x & 63;
    const int wave = threadIdx.x >> 6;
    const int chunk  = ((blockIdx.x & 3) << 2) | wave;   // 0..15
    const int row_id = blockIdx.x >> 2;                  // 0..4079
    const int yo = row_id % YOv;
    int r2 = row_id / YOv;
    const int to = r2 & 7;
    const int b  = r2 >> 3;
    const int px  = chunk & 1;
    const int cb8 = chunk >> 1;
    const int m = lane & 15, q = lane >> 4;
    const int cxm = cb8 * 16 + m;

    __shared__ float shsum[64], shsq[64];
    if (threadIdx.x < 64) { shsum[threadIdx.x] = 0.f; shsq[threadIdx.x] = 0.f; }
    __syncthreads();

    int xcx[2], xkx[2], nx;
    if (px == 0) { nx = 1; xcx[0] = cxm; xkx[0] = 1; }
    else { nx = 2; xcx[0] = (cxm + 1 > 127) ? 127 : cxm + 1; xkx[0] = 0; xcx[1] = cxm; xkx[1] = 2; }
    int ycy[2], yky[2], ny;
    if ((yo & 1) == 0) { ny = 1; ycy[0] = yo >> 1; yky[0] = 1; }
    else { ny = 2; ycy[0] = (yo + 1) >> 1; yky[0] = 0; ycy[1] = (yo - 1) >> 1; yky[1] = 2; }

    f32x4 acc[4];
    #pragma unroll
    for (int i = 0; i < 4; ++i) acc[i] = (f32x4){0.f, 0.f, 0.f, 0.f};

    for (int kt = 0; kt < 3; ++kt) {
        int ct = to + 1 - kt;
        if (ct < 0 || ct >= TT) continue;
        for (int iy = 0; iy < ny; ++iy) {
            int wbase = (kt * 3 + yky[iy]) * 3;
            size_t plane = ((size_t)((b * TT + ct) * YY + ycy[iy])) * XX;
            for (int ix = 0; ix < nx; ++ix) {
                const unsigned short* arow = Dbf + (plane + (size_t)xcx[ix]) * CINv;
                FragU A[4];
                #pragma unroll
                for (int kc = 0; kc < 4; ++kc)
                    A[kc].u = *(const u32x4*)(arow + kc * 32 + q * 8);
                const unsigned short* pb = PB + ((size_t)(wbase + xkx[ix]) * 16 * 64) * 8;
                #pragma unroll
                for (int nt = 0; nt < 4; ++nt) {
                    #pragma unroll
                    for (int kc = 0; kc < 4; ++kc) {
                        FragU Bf;
                        Bf.u = *(const u32x4*)(pb + ((size_t)(kc * 4 + nt) * 64 + lane) * 8);
                        acc[nt] = __builtin_amdgcn_mfma_f32_16x16x32_bf16(A[kc].b, Bf.b, acc[nt], 0, 0, 0);
                    }
                }
            }
        }
    }

    // epilogue: store + per-channel partial stats
    size_t rowbase = ((size_t)((b * TT + to) * YOv + yo)) * XOv;
    float sl[4], sq[4];
    #pragma unroll
    for (int nt = 0; nt < 4; ++nt) { sl[nt] = 0.f; sq[nt] = 0.f; }
    #pragma unroll
    for (int nt = 0; nt < 4; ++nt) {
        int c = nt * 16 + m;
        #pragma unroll
        for (int i = 0; i < 4; ++i) {
            int rr = q * 4 + i;
            int xo = 2 * (cb8 * 16 + rr) + px;
            if (xo < XOv) {
                float v = acc[nt][i];
                out[(rowbase + xo) * COUTv + c] = v;
                sl[nt] += v; sq[nt] += v * v;
            }
        }
    }
    // reduce across the 4 q-groups (same channel lives in lanes m, m+16, m+32, m+48)
    #pragma unroll
    for (int nt = 0; nt < 4; ++nt) {
        sl[nt] += __shfl_xor(sl[nt], 16); sl[nt] += __shfl_xor(sl[nt], 32);
        sq[nt] += __shfl_xor(sq[nt], 16); sq[nt] += __shfl_xor(sq[nt], 32);
    }
    if (lane < 16) {
        #pragma unroll
        for (int nt = 0; nt < 4; ++nt) {
            atomicAdd(&shsum[nt * 16 + lane], sl[nt]);
            atomicAdd(&shsq [nt * 16 + lane], sq[nt]);
        }
    }
    __syncthreads();
    if (threadIdx.x < 64) {
        unsafeAtomicAdd(&gsum[threadIdx.x], shsum[threadIdx.x]);
        unsafeAtomicAdd(&gsq [threadIdx.x], shsq [threadIdx.x]);
    }
}

// ---------------- pass 6: finalize BN stats ----------------
__global__ __launch_bounds__(64) void k_final(
    const float* __restrict__ gsum, const float* __restrict__ gsq,
    const unsigned int* __restrict__ ncnt,
    const float* __restrict__ gamma, const float* __restrict__ beta,
    float* __restrict__ scale, float* __restrict__ shift)
{
    int c = threadIdx.x;
    float nf = (float)max(*ncnt, 1u);
    float mean = gsum[c] / nf;
    float var  = gsq[c] / nf - mean * mean;
    float rstd = rsqrtf(var + 1e-5f);
    float sc = rstd * gamma[c];
    scale[c] = sc;
    shift[c] = beta[c] - mean * sc;
}

// ---------------- pass 7: normalize + mask + relu (in place) ----------------
__global__ __launch_bounds__(256) void k_norm(
    float* __restrict__ out, const unsigned char* __restrict__ mask,
    const float* __restrict__ scale, const float* __restrict__ shift)
{
    __shared__ float ssc[64], ssh[64];
    if (threadIdx.x < 64) { ssc[threadIdx.x] = scale[threadIdx.x]; ssh[threadIdx.x] = shift[threadIdx.x]; }
    __syncthreads();
    size_t t = (size_t)blockIdx.x * 256 + threadIdx.x;   // 16,646,400 threads exactly
    size_t e = t * 4;
    float4 v = ((float4*)out)[t];
    int c = (int)(e & 63);
    size_t site = e >> 6;
    if (mask[site]) {
        v.x = fmaxf(fmaf(v.x, ssc[c + 0], ssh[c + 0]), 0.f);
        v.y = fmaxf(fmaf(v.y, ssc[c + 1], ssh[c + 1]), 0.f);
        v.z = fmaxf(fmaf(v.z, ssc[c + 2], ssh[c + 2]), 0.f);
        v.w = fmaxf(fmaf(v.w, ssc[c + 3], ssh[c + 3]), 0.f);
    } else {
        v.x = v.y = v.z = v.w = 0.f;
    }
    ((float4*)out)[t] = v;
}

// ---------------- launch ----------------
extern "C" void kernel_launch(void* const* d_in, const int* in_sizes, int n_in,
                              void* d_out, int out_size, void* d_ws, size_t ws_size,
                              hipStream_t stream)
{
    const float* feats = (const float*)d_in[0];
    const float* W     = (const float*)d_in[1];
    const float* gamma = (const float*)d_in[2];
    const float* beta  = (const float*)d_in[3];
    const int* cb = (const int*)d_in[4];
    const int* ct = (const int*)d_in[5];
    const int* cy = (const int*)d_in[6];
    const int* cx = (const int*)d_in[7];
    float* out = (float*)d_out;

    char* ws = (char*)d_ws;
    float*          gsum = (float*)(ws + OFF_STATS);
    float*          gsq  = gsum + 64;
    unsigned int*   ncnt = (unsigned int*)(ws + OFF_STATS + 512);
    unsigned int*   cnt  = (unsigned int*)(ws + OFF_CNT);
    int*            idx  = (int*)(ws + OFF_IDX);
    unsigned short* Dbf  = (unsigned short*)(ws + OFF_DBF);
    unsigned short* PB   = (unsigned short*)(ws + OFF_PB);
    unsigned char*  mask = (unsigned char*)(ws + OFF_MASK);
    float*          scale= (float*)(ws + OFF_SS);
    float*          shift= scale + 64;

    hipMemsetAsync(d_ws, 0, ZERO_BYTES, stream);

    k_count<<<NVOX / 256, 256, 0, stream>>>(cb, ct, cy, cx, cnt, idx);
    k_gather<<<NSITES * 16 / 256, 256, 0, stream>>>(feats, cnt, idx, Dbf);
    k_pack<<<27 * 16, 64, 0, stream>>>(W, PB);
    k_mask<<<(OUT_SITES + 255) / 256, 256, 0, stream>>>(cnt, mask, ncnt);
    k_conv<<<BB * TT * YOv * 4, 256, 0, stream>>>(Dbf, PB, out, gsum, gsq);
    k_final<<<1, 64, 0, stream>>>(gsum, gsq, ncnt, gamma, beta, scale, shift);
    k_norm<<<(int)(OUT_ELEMS / 4 / 256), 256, 0, stream>>>(out, mask, scale, shift);
}

// Round 3
// 820.364 us; speedup vs baseline: 1.8834x; 1.3640x over previous
//
#include <hip/hip_runtime.h>
#include <hip/hip_bf16.h>

// ---------------- problem constants ----------------
#define BB   2
#define TT   8
#define YY   128
#define XX   128
#define CINv 128
#define COUTv 64
#define YOv  255
#define XOv  255
#define NVOX 262144
#define NSITES (BB*TT*YY*XX)                 // 262,144 input sites
#define CAP  16
#define OUT_SITES (BB*TT*YOv*XOv)            // 1,040,400
#define OUT_ELEMS ((size_t)OUT_SITES*COUTv)  // 66,585,600

typedef float  f32x4  __attribute__((ext_vector_type(4)));
typedef __bf16 bf16x8 __attribute__((ext_vector_type(8)));
typedef unsigned int u32x4 __attribute__((ext_vector_type(4)));

union FragU { u32x4 u; bf16x8 b; };
union Pack8 { unsigned short s[8]; u32x4 u; };

// ---------------- workspace layout (bytes) ----------------
constexpr size_t OFF_STATS = 0;                          // gsum[64]@0, gsq[64]@256, ncnt@512
constexpr size_t OFF_CNT   = 1024;                       // 262144*4 = 1,048,576
constexpr size_t ZERO_BYTES= OFF_CNT + 1048576;          // 1,049,600
constexpr size_t OFF_DBF   = ZERO_BYTES;                 // 262144*128*2 = 67,108,864
constexpr size_t OFF_PB    = OFF_DBF + 67108864;         // 27*16*64*8*2 = 442,368
constexpr size_t OFF_MASK  = OFF_PB + 442368;            // 1,040,400 (pad 1 MiB)
constexpr size_t OFF_SS    = OFF_MASK + 1048576;         // scale[64], shift[64]
// idx (used only by k_count/k_gather) aliases outb (used only by k_conv/k_norm)
constexpr size_t OFF_IDX   = OFF_SS + 1024;              // 262144*16*4 = 16,777,216
constexpr size_t OFF_OUTB  = OFF_IDX;                    // OUT_ELEMS*2 = 133,171,200
// total ~193.4 MiB (< round-0 footprint)

__device__ __forceinline__ unsigned short f2bf(float f) {
    unsigned u = __float_as_uint(f);
    u += 0x7fffu + ((u >> 16) & 1u);       // round-to-nearest-even
    return (unsigned short)(u >> 16);
}

__device__ __forceinline__ void gld16(const void* g, void* l) {
    __builtin_amdgcn_global_load_lds(
        (const __attribute__((address_space(1))) unsigned int*)g,
        (__attribute__((address_space(3))) unsigned int*)l, 16, 0, 0);
}

// ---------------- pass 1: per-site voxel lists ----------------
__global__ __launch_bounds__(256) void k_count(
    const int* __restrict__ cb, const int* __restrict__ ct,
    const int* __restrict__ cy, const int* __restrict__ cx,
    unsigned int* __restrict__ cnt, int* __restrict__ idx)
{
    int n = blockIdx.x * 256 + threadIdx.x;     // NVOX threads
    int site = ((cb[n] * TT + ct[n]) * YY + cy[n]) * XX + cx[n];
    unsigned slot = atomicAdd(cnt + site, 1u);
    if (slot < CAP) idx[site * CAP + slot] = n;  // P(overflow) ~ 4e-9 for Poisson(1)
}

// ---------------- pass 2: gather-sum feats -> bf16 dense grid ----------------
__global__ __launch_bounds__(256) void k_gather(
    const float* __restrict__ feats,
    const unsigned int* __restrict__ cnt, const int* __restrict__ idx,
    unsigned short* __restrict__ Dbf)
{
    int tid = blockIdx.x * 256 + threadIdx.x;   // NSITES*16 threads
    int site = tid >> 4;
    int c8 = (tid & 15) * 8;
    unsigned c = cnt[site]; if (c > CAP) c = CAP;
    float a[8] = {0.f,0.f,0.f,0.f,0.f,0.f,0.f,0.f};
    const int* ip = idx + (size_t)site * CAP;
    for (unsigned v = 0; v < c; ++v) {
        int n = ip[v];
        const float4 f0 = *(const float4*)(feats + (size_t)n * CINv + c8);
        const float4 f1 = *(const float4*)(feats + (size_t)n * CINv + c8 + 4);
        a[0] += f0.x; a[1] += f0.y; a[2] += f0.z; a[3] += f0.w;
        a[4] += f1.x; a[5] += f1.y; a[6] += f1.z; a[7] += f1.w;
    }
    Pack8 p;
    #pragma unroll
    for (int j = 0; j < 8; ++j) p.s[j] = f2bf(a[j]);
    *(u32x4*)(Dbf + (size_t)site * CINv + c8) = p.u;
}

// ---------------- pass 3: pack weights into MFMA B-fragments ----------------
// PB layout: [w(27)][f(16)=kc*4+nt][lane(64)][8 bf16]  (16 KB per tap tile)
__global__ __launch_bounds__(64) void k_pack(
    const float* __restrict__ W, unsigned short* __restrict__ PB)
{
    int f = blockIdx.x;                 // 0..431 = w*16 + kc*4 + nt
    int w  = f >> 4;
    int kc = (f >> 2) & 3;
    int nt = f & 3;
    int lane = threadIdx.x;
    int q = lane >> 4, col = lane & 15;
    Pack8 p;
    #pragma unroll
    for (int j = 0; j < 8; ++j) {
        int k  = kc * 32 + q * 8 + j;
        int nn = nt * 16 + col;
        p.s[j] = f2bf(W[((size_t)w * CINv + k) * COUTv + nn]);
    }
    *(u32x4*)(PB + ((size_t)f * 64 + lane) * 8) = p.u;
}

// ---------------- pass 4: active-site mask + count ----------------
__global__ __launch_bounds__(256) void k_mask(
    const unsigned int* __restrict__ occ,
    unsigned char* __restrict__ mask, unsigned int* __restrict__ ncnt)
{
    int s = blockIdx.x * 256 + threadIdx.x;
    bool found = false;
    if (s < OUT_SITES) {
        int xo = s % XOv; int r = s / XOv;
        int yo = r % YOv; r /= YOv;
        int to = r & 7;   int b = r >> 3;
        int cts[3]; int ntc = 0;
        for (int kt = 0; kt < 3; ++kt) { int c = to + 1 - kt; if (c >= 0 && c < TT) cts[ntc++] = c; }
        int cys[2]; int nyc;
        if (yo & 1) { cys[0] = (yo + 1) >> 1; cys[1] = (yo - 1) >> 1; nyc = 2; }
        else        { cys[0] = yo >> 1; nyc = 1; }
        int cxs[2]; int nxc;
        if (xo & 1) { cxs[0] = (xo + 1) >> 1; cxs[1] = (xo - 1) >> 1; nxc = 2; }
        else        { cxs[0] = xo >> 1; nxc = 1; }
        for (int i = 0; i < ntc && !found; ++i)
            for (int j = 0; j < nyc && !found; ++j)
                for (int k = 0; k < nxc && !found; ++k)
                    if (occ[((b * TT + cts[i]) * YY + cys[j]) * XX + cxs[k]]) found = true;
        mask[s] = found ? 1 : 0;
    }
    unsigned long long bal = __ballot(found);
    if ((threadIdx.x & 63) == 0) {
        unsigned c = (unsigned)__popcll(bal);
        if (c) atomicAdd(ncnt, c);
    }
}

// ---------------- pass 5: MFMA transpose-conv, LDS-staged B ----------------
// Block = one output row (b,to,yo), 4 waves. Wave w handles 4 x-chunks:
// (cb8=2w,px=0),(2w,1),(2w+1,0),(2w+1,1). Per (kt,ky): stage 3 kx tiles
// (48 KB) into LDS once, then per kx read each B frag once and MFMA it
// into both matching-parity chunks.
__global__ __launch_bounds__(256, 3) void k_conv(
    const unsigned short* __restrict__ Dbf,
    const unsigned short* __restrict__ PB,
    unsigned short* __restrict__ outb,
    float* __restrict__ gsum, float* __restrict__ gsq)
{
    const int lane = threadIdx.x & 63;
    const int wave = threadIdx.x >> 6;
    const int row_id = blockIdx.x;               // 0..4079
    const int yo = row_id % YOv;
    int r2 = row_id / YOv;
    const int to = r2 & 7;
    const int b  = r2 >> 3;
    const int m = lane & 15, q = lane >> 4;

    __shared__ __align__(16) unsigned short shB[3 * 16 * 64 * 8];   // 48 KB
    __shared__ float shsum[64], shsq[64];
    if (threadIdx.x < 64) { shsum[threadIdx.x] = 0.f; shsq[threadIdx.x] = 0.f; }

    int ycy[2], yky[2], ny;
    if ((yo & 1) == 0) { ny = 1; ycy[0] = yo >> 1; yky[0] = 1; }
    else { ny = 2; ycy[0] = (yo + 1) >> 1; yky[0] = 0; ycy[1] = (yo - 1) >> 1; yky[1] = 2; }

    f32x4 acc[4][4];   // [chunk][nt]
    #pragma unroll
    for (int ch = 0; ch < 4; ++ch)
        #pragma unroll
        for (int nt = 0; nt < 4; ++nt) acc[ch][nt] = (f32x4){0.f, 0.f, 0.f, 0.f};

    for (int kt = 0; kt < 3; ++kt) {
        int ct = to + 1 - kt;
        if (ct < 0 || ct >= TT) continue;        // uniform over block
        for (int iy = 0; iy < ny; ++iy) {        // uniform over block
            __syncthreads();                      // protect LDS from prior readers
            {
                const char* gsrc = (const char*)PB + (size_t)((kt * 3 + yky[iy]) * 3) * 16384;
                char* ldst = (char*)shB;
                #pragma unroll
                for (int r = 0; r < 12; ++r)
                    gld16(gsrc + r * 4096 + threadIdx.x * 16,
                          ldst + r * 4096 + wave * 1024);
            }
            __syncthreads();

            size_t plane = ((size_t)((b * TT + ct) * YY + ycy[iy])) * XX;
            #pragma unroll
            for (int kx = 0; kx < 3; ++kx) {
                const int cxoff = (kx == 0) ? 1 : 0;
                const int ca = (kx == 1) ? 0 : 1;         // acc slot for cb8=2w
                int cxa = (2 * wave) * 16 + m + cxoff;     if (cxa > 127) cxa = 127;
                int cxb = (2 * wave + 1) * 16 + m + cxoff; if (cxb > 127) cxb = 127;
                const unsigned short* Ara = Dbf + (plane + (size_t)cxa) * CINv;
                const unsigned short* Arb = Dbf + (plane + (size_t)cxb) * CINv;
                FragU Aa[4], Ab[4];
                #pragma unroll
                for (int kc = 0; kc < 4; ++kc) {
                    Aa[kc].u = *(const u32x4*)(Ara + kc * 32 + q * 8);
                    Ab[kc].u = *(const u32x4*)(Arb + kc * 32 + q * 8);
                }
                const unsigned short* bt = shB + kx * 8192;
                #pragma unroll
                for (int kc = 0; kc < 4; ++kc) {
                    FragU Bf[4];
                    #pragma unroll
                    for (int nt = 0; nt < 4; ++nt)
                        Bf[nt].u = *(const u32x4*)(bt + (size_t)((kc * 4 + nt) * 64 + lane) * 8);
                    #pragma unroll
                    for (int nt = 0; nt < 4; ++nt) {
                        acc[ca][nt]     = __builtin_amdgcn_mfma_f32_16x16x32_bf16(Aa[kc].b, Bf[nt].b, acc[ca][nt], 0, 0, 0);
                        acc[ca + 2][nt] = __builtin_amdgcn_mfma_f32_16x16x32_bf16(Ab[kc].b, Bf[nt].b, acc[ca + 2][nt], 0, 0, 0);
                    }
                }
            }
        }
    }

    // epilogue: bf16 store + per-channel partial stats
    size_t rowbase = ((size_t)((b * TT + to) * YOv + yo)) * XOv;
    float sl[4] = {0.f,0.f,0.f,0.f}, sq[4] = {0.f,0.f,0.f,0.f};
    #pragma unroll
    for (int ch = 0; ch < 4; ++ch) {
        int cb8 = 2 * wave + (ch >> 1);
        int px = ch & 1;
        #pragma unroll
        for (int nt = 0; nt < 4; ++nt) {
            int c = nt * 16 + m;
            #pragma unroll
            for (int i = 0; i < 4; ++i) {
                int r = q * 4 + i;
                int xo = 2 * (cb8 * 16 + r) + px;
                if (xo < XOv) {
                    float v = acc[ch][nt][i];
                    outb[(rowbase + xo) * COUTv + c] = f2bf(v);
                    sl[nt] += v; sq[nt] += v * v;
                }
            }
        }
    }
    #pragma unroll
    for (int nt = 0; nt < 4; ++nt) {
        sl[nt] += __shfl_xor(sl[nt], 16); sl[nt] += __shfl_xor(sl[nt], 32);
        sq[nt] += __shfl_xor(sq[nt], 16); sq[nt] += __shfl_xor(sq[nt], 32);
    }
    if (lane < 16) {
        #pragma unroll
        for (int nt = 0; nt < 4; ++nt) {
            atomicAdd(&shsum[nt * 16 + lane], sl[nt]);
            atomicAdd(&shsq [nt * 16 + lane], sq[nt]);
        }
    }
    __syncthreads();
    if (threadIdx.x < 64) {
        unsafeAtomicAdd(&gsum[threadIdx.x], shsum[threadIdx.x]);
        unsafeAtomicAdd(&gsq [threadIdx.x], shsq [threadIdx.x]);
    }
}

// ---------------- pass 6: finalize BN stats ----------------
__global__ __launch_bounds__(64) void k_final(
    const float* __restrict__ gsum, const float* __restrict__ gsq,
    const unsigned int* __restrict__ ncnt,
    const float* __restrict__ gamma, const float* __restrict__ beta,
    float* __restrict__ scale, float* __restrict__ shift)
{
    int c = threadIdx.x;
    float nf = (float)max(*ncnt, 1u);
    float mean = gsum[c] / nf;
    float var  = gsq[c] / nf - mean * mean;
    float rstd = rsqrtf(var + 1e-5f);
    float sc = rstd * gamma[c];
    scale[c] = sc;
    shift[c] = beta[c] - mean * sc;
}

// ---------------- pass 7: normalize + mask + relu (bf16 -> fp32) ----------------
__global__ __launch_bounds__(256) void k_norm(
    const unsigned short* __restrict__ outb, float* __restrict__ out,
    const unsigned char* __restrict__ mask,
    const float* __restrict__ scale, const float* __restrict__ shift)
{
    __shared__ float ssc[64], ssh[64];
    if (threadIdx.x < 64) { ssc[threadIdx.x] = scale[threadIdx.x]; ssh[threadIdx.x] = shift[threadIdx.x]; }
    __syncthreads();
    size_t t = (size_t)blockIdx.x * 256 + threadIdx.x;
    size_t e = t * 8;
    if (e >= OUT_ELEMS) return;
    Pack8 p; p.u = *(const u32x4*)(outb + e);
    int c = (int)(e & 63);
    size_t site = e >> 6;
    float4 v0, v1;
    if (mask[site]) {
        float w[8];
        #pragma unroll
        for (int j = 0; j < 8; ++j) {
            float f = __uint_as_float((unsigned)p.s[j] << 16);
            w[j] = fmaxf(fmaf(f, ssc[c + j], ssh[c + j]), 0.f);
        }
        v0 = make_float4(w[0], w[1], w[2], w[3]);
        v1 = make_float4(w[4], w[5], w[6], w[7]);
    } else {
        v0 = make_float4(0.f, 0.f, 0.f, 0.f);
        v1 = v0;
    }
    *(float4*)(out + e) = v0;
    *(float4*)(out + e + 4) = v1;
}

// ---------------- launch ----------------
extern "C" void kernel_launch(void* const* d_in, const int* in_sizes, int n_in,
                              void* d_out, int out_size, void* d_ws, size_t ws_size,
                              hipStream_t stream)
{
    const float* feats = (const float*)d_in[0];
    const float* W     = (const float*)d_in[1];
    const float* gamma = (const float*)d_in[2];
    const float* beta  = (const float*)d_in[3];
    const int* cb = (const int*)d_in[4];
    const int* ct = (const int*)d_in[5];
    const int* cy = (const int*)d_in[6];
    const int* cx = (const int*)d_in[7];
    float* out = (float*)d_out;

    char* ws = (char*)d_ws;
    float*          gsum = (float*)(ws + OFF_STATS);
    float*          gsq  = gsum + 64;
    unsigned int*   ncnt = (unsigned int*)(ws + OFF_STATS + 512);
    unsigned int*   cnt  = (unsigned int*)(ws + OFF_CNT);
    unsigned short* Dbf  = (unsigned short*)(ws + OFF_DBF);
    unsigned short* PB   = (unsigned short*)(ws + OFF_PB);
    unsigned char*  mask = (unsigned char*)(ws + OFF_MASK);
    float*          scale= (float*)(ws + OFF_SS);
    float*          shift= scale + 64;
    int*            idx  = (int*)(ws + OFF_IDX);
    unsigned short* outb = (unsigned short*)(ws + OFF_OUTB);   // aliases idx (ordered)

    hipMemsetAsync(d_ws, 0, ZERO_BYTES, stream);

    k_count<<<NVOX / 256, 256, 0, stream>>>(cb, ct, cy, cx, cnt, idx);
    k_gather<<<NSITES * 16 / 256, 256, 0, stream>>>(feats, cnt, idx, Dbf);
    k_pack<<<27 * 16, 64, 0, stream>>>(W, PB);
    k_mask<<<(OUT_SITES + 255) / 256, 256, 0, stream>>>(cnt, mask, ncnt);
    k_conv<<<BB * TT * YOv, 256, 0, stream>>>(Dbf, PB, outb, gsum, gsq);
    k_final<<<1, 64, 0, stream>>>(gsum, gsq, ncnt, gamma, beta, scale, shift);
    k_norm<<<(int)((OUT_ELEMS / 8 + 255) / 256), 256, 0, stream>>>(outb, out, mask, scale, shift);
}